// Round 5
// baseline (1113.701 us; speedup 1.0000x reference)
//
#include <hip/hip_runtime.h>

#define N_NODES 100000
#define N_EDGES 3200000
#define F_IN    512
#define HIDDEN  16
#define N_CLASS 10

#define NBUCK 784        // dst buckets of 128 nodes: 784*128 = 100352 >= N_NODES
#define BSH   7
#define BMASK 127
#define EPB   8192       // edges per partition block
#define NPART ((N_EDGES + EPB - 1) / EPB)   // 391
#define ASTR  17         // LDS accumulator stride (floats): odd -> bank spread

// index load robust to int32/int64 (is32 nonzero => int32)
__device__ __forceinline__ int load_idx(const void* ei, int is32, long long pos) {
    return is32 ? ((const int*)ei)[pos] : (int)((const long long*)ei)[pos];
}

__global__ void k_zeroi(int* __restrict__ p, int n) {
    int i = blockIdx.x * 256 + threadIdx.x;
    if (i < n) p[i] = 0;
}

// int64 storage (values < 2^31) => all odd 32-bit words are 0; int32 => mostly nonzero.
__global__ void k_detect(const unsigned* __restrict__ ei, int* __restrict__ det) {
    int t = threadIdx.x;
    unsigned odd = 0;
    for (int i = t; i < 4096; i += 256) odd |= ei[2 * i + 1];   // 32KB read, safe either way
    if (odd) atomicOr(&det[0], 1);
}

// per-block LDS histogram of dst buckets -> global bucket sizes
__global__ __launch_bounds__(256) void k_bhist(const void* __restrict__ ei,
                                               const int* __restrict__ det,
                                               int* __restrict__ bsize) {
    __shared__ int hist[NBUCK];
    int t = threadIdx.x;
    long long e0 = (long long)blockIdx.x * EPB;
    long long e1 = e0 + EPB; if (e1 > N_EDGES) e1 = N_EDGES;
    int is32 = det[0];
    for (int i = t; i < NBUCK; i += 256) hist[i] = 0;
    __syncthreads();
    for (long long e = e0 + t; e < e1; e += 256) {
        int d = load_idx(ei, is32, N_EDGES + e);
        atomicAdd(&hist[d >> BSH], 1);
    }
    __syncthreads();
    for (int i = t; i < NBUCK; i += 256)
        if (hist[i]) atomicAdd(&bsize[i], hist[i]);
}

// exclusive scan of 784 bucket sizes -> bbase (read-only) and bcur (atomic cursors)
__global__ void k_bucketscan(const int* __restrict__ bsize, int* __restrict__ bbase,
                             int* __restrict__ bcur) {
    __shared__ int s[1024];
    int t = threadIdx.x;
    int v = (t < NBUCK) ? bsize[t] : 0;
    s[t] = v;
    __syncthreads();
    for (int off = 1; off < 1024; off <<= 1) {
        int u = (t >= off) ? s[t - off] : 0;
        __syncthreads();
        s[t] += u;
        __syncthreads();
    }
    if (t < NBUCK) { int ex = s[t] - v; bbase[t] = ex; bcur[t] = ex; }
}

// partition edges into dst buckets; packed word = (s<<7)|(d&127) (24 bits)
__global__ __launch_bounds__(256) void k_part(const void* __restrict__ ei,
                                              const int* __restrict__ det,
                                              int* __restrict__ bcur,
                                              unsigned* __restrict__ buf) {
    __shared__ int hist[NBUCK];
    __shared__ int base[NBUCK];
    __shared__ int lcur[NBUCK];
    int t = threadIdx.x;
    long long e0 = (long long)blockIdx.x * EPB;
    long long e1 = e0 + EPB; if (e1 > N_EDGES) e1 = N_EDGES;
    int is32 = det[0];
    for (int i = t; i < NBUCK; i += 256) { hist[i] = 0; lcur[i] = 0; }
    __syncthreads();
    for (long long e = e0 + t; e < e1; e += 256) {
        int d = load_idx(ei, is32, N_EDGES + e);
        atomicAdd(&hist[d >> BSH], 1);
    }
    __syncthreads();
    for (int i = t; i < NBUCK; i += 256)
        base[i] = hist[i] ? atomicAdd(&bcur[i], hist[i]) : 0;
    __syncthreads();
    for (long long e = e0 + t; e < e1; e += 256) {
        int s = load_idx(ei, is32, e);
        int d = load_idx(ei, is32, (long long)N_EDGES + e);
        int b = d >> BSH;
        int off = atomicAdd(&lcur[b], 1);
        buf[base[b] + off] = ((unsigned)s << BSH) | (unsigned)(d & BMASK);
    }
}

// per-bucket degree count -> dinv = rsqrt(deg+1). No global deg array needed.
__global__ __launch_bounds__(256) void k_degb(const unsigned* __restrict__ buf,
                                              const int* __restrict__ bbase,
                                              const int* __restrict__ bsize,
                                              float* __restrict__ dinv) {
    __shared__ int cnt[128];
    int t = threadIdx.x;
    int b = blockIdx.x;
    if (t < 128) cnt[t] = 0;
    __syncthreads();
    int j0 = bbase[b], j1 = j0 + bsize[b];
    for (int j = j0 + t; j < j1; j += 256)
        atomicAdd(&cnt[buf[j] & BMASK], 1);
    __syncthreads();
    if (t < 128) {
        int n = (b << BSH) + t;
        if (n < N_NODES) dinv[n] = rsqrtf((float)(cnt[t] + 1));
    }
}

// hs[N][16] = (x @ W1) * dinv[row].  Thread-per-row register GEMV:
// x streamed as float4 (lines fully consumed via L1); W1 loads are wave-uniform -> s_load.
__global__ __launch_bounds__(256) void k_gemv1(const float* __restrict__ x,
                                               const float* __restrict__ W1,
                                               const float* __restrict__ dinv,
                                               float* __restrict__ hs) {
    int n = blockIdx.x * 256 + threadIdx.x;
    if (n >= N_NODES) return;
    const float4* xr = (const float4*)(x + (size_t)n * F_IN);
    float acc[16];
#pragma unroll
    for (int k = 0; k < 16; ++k) acc[k] = 0.f;
#pragma unroll 1
    for (int j = 0; j < F_IN; j += 16) {
        float4 a0 = xr[(j >> 2) + 0];
        float4 a1 = xr[(j >> 2) + 1];
        float4 a2 = xr[(j >> 2) + 2];
        float4 a3 = xr[(j >> 2) + 3];
        float xs[16] = { a0.x, a0.y, a0.z, a0.w,  a1.x, a1.y, a1.z, a1.w,
                         a2.x, a2.y, a2.z, a2.w,  a3.x, a3.y, a3.z, a3.w };
#pragma unroll
        for (int jj = 0; jj < 16; ++jj)
#pragma unroll
            for (int k = 0; k < 16; ++k)
                acc[k] += xs[jj] * W1[(j + jj) * HIDDEN + k];
    }
    float di = dinv[n];
    float4* o = (float4*)&hs[(size_t)n * HIDDEN];
    o[0] = make_float4(acc[0] * di, acc[1] * di, acc[2] * di, acc[3] * di);
    o[1] = make_float4(acc[4] * di, acc[5] * di, acc[6] * di, acc[7] * di);
    o[2] = make_float4(acc[8] * di, acc[9] * di, acc[10] * di, acc[11] * di);
    o[3] = make_float4(acc[12] * di, acc[13] * di, acc[14] * di, acc[15] * di);
}

// layer-1 aggregation: one bucket per block, edge-parallel into LDS accumulator,
// then fused bias + ReLU + (16->10) W2 + dinv pre-scale epilogue -> ts[N][16].
__global__ __launch_bounds__(256) void k_agg1(const unsigned* __restrict__ buf,
                                              const int* __restrict__ bbase,
                                              const int* __restrict__ bsize,
                                              const float* __restrict__ hs,
                                              const float* __restrict__ dinv,
                                              const float* __restrict__ b1,
                                              const float* __restrict__ W2,
                                              float* __restrict__ ts) {
    __shared__ float accL[128 * ASTR];
    int t = threadIdx.x;
    int b = blockIdx.x;
    for (int i = t; i < 128 * ASTR; i += 256) accL[i] = 0.f;
    __syncthreads();
    int j0 = bbase[b], j1 = j0 + bsize[b];
    int g = t >> 2, q = (t & 3) << 2;     // 64 groups x 4 feature-lanes
    int j = j0 + g;
    for (; j + 64 < j1; j += 128) {       // 2-way unroll: overlap gather latency
        unsigned w0 = buf[j], w1 = buf[j + 64];
        float4 v0 = *(const float4*)&hs[(size_t)(w0 >> BSH) * HIDDEN + q];
        float4 v1 = *(const float4*)&hs[(size_t)(w1 >> BSH) * HIDDEN + q];
        float* a0 = &accL[(w0 & BMASK) * ASTR + q];
        atomicAdd(a0 + 0, v0.x); atomicAdd(a0 + 1, v0.y);
        atomicAdd(a0 + 2, v0.z); atomicAdd(a0 + 3, v0.w);
        float* a1 = &accL[(w1 & BMASK) * ASTR + q];
        atomicAdd(a1 + 0, v1.x); atomicAdd(a1 + 1, v1.y);
        atomicAdd(a1 + 2, v1.z); atomicAdd(a1 + 3, v1.w);
    }
    if (j < j1) {
        unsigned w0 = buf[j];
        float4 v0 = *(const float4*)&hs[(size_t)(w0 >> BSH) * HIDDEN + q];
        float* a0 = &accL[(w0 & BMASK) * ASTR + q];
        atomicAdd(a0 + 0, v0.x); atomicAdd(a0 + 1, v0.y);
        atomicAdd(a0 + 2, v0.z); atomicAdd(a0 + 3, v0.w);
    }
    __syncthreads();
    int k = t & 15;
    // phase A: h = relu(dinv*(agg + self) + b1), written back to accL
#pragma unroll
    for (int p = 0; p < 8; ++p) {
        int ln = p * 16 + (t >> 4);
        int n = (b << BSH) + ln;
        if (n < N_NODES) {
            float di = dinv[n];
            float h = di * (accL[ln * ASTR + k] + hs[(size_t)n * HIDDEN + k]) + b1[k];
            accL[ln * ASTR + k] = h > 0.f ? h : 0.f;
        }
    }
    __syncthreads();
    // phase B: o[c] = sum_kk h[kk]*W2[kk][c]; ts = o * dinv (pre-scale for layer 2)
    int c = (k < N_CLASS) ? k : 0;
#pragma unroll
    for (int p = 0; p < 8; ++p) {
        int ln = p * 16 + (t >> 4);
        int n = (b << BSH) + ln;
        if (n < N_NODES) {
            float o = 0.f;
#pragma unroll
            for (int kk = 0; kk < HIDDEN; ++kk)
                o += accL[ln * ASTR + kk] * W2[kk * N_CLASS + c];
            ts[(size_t)n * 16 + k] = (k < N_CLASS) ? o * dinv[n] : 0.f;
        }
    }
}

// layer-2 aggregation: same bucket structure, ts -> out with bias
__global__ __launch_bounds__(256) void k_agg2(const unsigned* __restrict__ buf,
                                              const int* __restrict__ bbase,
                                              const int* __restrict__ bsize,
                                              const float* __restrict__ ts,
                                              const float* __restrict__ dinv,
                                              const float* __restrict__ b2,
                                              float* __restrict__ out) {
    __shared__ float accL[128 * ASTR];
    int t = threadIdx.x;
    int b = blockIdx.x;
    for (int i = t; i < 128 * ASTR; i += 256) accL[i] = 0.f;
    __syncthreads();
    int j0 = bbase[b], j1 = j0 + bsize[b];
    int g = t >> 2, q = (t & 3) << 2;
    int j = j0 + g;
    for (; j + 64 < j1; j += 128) {
        unsigned w0 = buf[j], w1 = buf[j + 64];
        float4 v0 = *(const float4*)&ts[(size_t)(w0 >> BSH) * 16 + q];
        float4 v1 = *(const float4*)&ts[(size_t)(w1 >> BSH) * 16 + q];
        float* a0 = &accL[(w0 & BMASK) * ASTR + q];
        atomicAdd(a0 + 0, v0.x); atomicAdd(a0 + 1, v0.y);
        atomicAdd(a0 + 2, v0.z); atomicAdd(a0 + 3, v0.w);
        float* a1 = &accL[(w1 & BMASK) * ASTR + q];
        atomicAdd(a1 + 0, v1.x); atomicAdd(a1 + 1, v1.y);
        atomicAdd(a1 + 2, v1.z); atomicAdd(a1 + 3, v1.w);
    }
    if (j < j1) {
        unsigned w0 = buf[j];
        float4 v0 = *(const float4*)&ts[(size_t)(w0 >> BSH) * 16 + q];
        float* a0 = &accL[(w0 & BMASK) * ASTR + q];
        atomicAdd(a0 + 0, v0.x); atomicAdd(a0 + 1, v0.y);
        atomicAdd(a0 + 2, v0.z); atomicAdd(a0 + 3, v0.w);
    }
    __syncthreads();
    int c = t & 15;
#pragma unroll
    for (int p = 0; p < 8; ++p) {
        int ln = p * 16 + (t >> 4);
        int n = (b << BSH) + ln;
        if (n < N_NODES && c < N_CLASS)
            out[(size_t)n * N_CLASS + c] =
                dinv[n] * (accL[ln * ASTR + c] + ts[(size_t)n * 16 + c]) + b2[c];
    }
}

extern "C" void kernel_launch(void* const* d_in, const int* in_sizes, int n_in,
                              void* d_out, int out_size, void* d_ws, size_t ws_size,
                              hipStream_t stream) {
    const float* x  = (const float*)d_in[0];   // fp32 [N,512]
    const void*  ei = d_in[1];                 // int64 (int32 handled via probe)
    const float* W1 = (const float*)d_in[2];   // fp32 [512,16]
    const float* b1 = (const float*)d_in[3];   // fp32 [16]
    const float* W2 = (const float*)d_in[4];   // fp32 [16,10]
    const float* b2 = (const float*)d_in[5];   // fp32 [10]
    float* out = (float*)d_out;                // fp32 [N,10]
    float* ws  = (float*)d_ws;

    // ws layout (4-byte units), ~26.0 MB total
    float*    dinv  = ws;                      // 100,096
    int*      bsize = (int*)(ws + 100096);     // 1,024
    int*      bbase = (int*)(ws + 101120);     // 1,024
    int*      bcur  = (int*)(ws + 102144);     // 1,024
    int*      det   = (int*)(ws + 103168);     // 64
    unsigned* buf   = (unsigned*)(ws + 103232);// 3,200,000 (lives through k_agg2)
    float*    hs    = ws + 3303232;            // 1,600,000
    float*    ts    = ws + 4903232;            // 1,600,000

    k_zeroi <<<(NBUCK + 255) / 256, 256, 0, stream>>>(bsize, NBUCK);
    k_zeroi <<<1, 64, 0, stream>>>(det, 1);
    k_detect<<<1, 256, 0, stream>>>((const unsigned*)ei, det);

    k_bhist     <<<NPART, 256, 0, stream>>>(ei, det, bsize);
    k_bucketscan<<<1, 1024, 0, stream>>>(bsize, bbase, bcur);
    k_part      <<<NPART, 256, 0, stream>>>(ei, det, bcur, buf);
    k_degb      <<<NBUCK, 256, 0, stream>>>(buf, bbase, bsize, dinv);

    k_gemv1<<<(N_NODES + 255) / 256, 256, 0, stream>>>(x, W1, dinv, hs);

    k_agg1<<<NBUCK, 256, 0, stream>>>(buf, bbase, bsize, hs, dinv, b1, W2, ts);
    k_agg2<<<NBUCK, 256, 0, stream>>>(buf, bbase, bsize, ts, dinv, b2, out);
}

// Round 6
// 626.939 us; speedup vs baseline: 1.7764x; 1.7764x over previous
//
#include <hip/hip_runtime.h>

#define N_NODES 100000
#define N_EDGES 3200000
#define F_IN    512
#define HIDDEN  16
#define N_CLASS 10

#define TILE_R  64
#define KC      64
#define XSTRIDE 68   // padded LDS stride (floats); %4==0 for b128, measured 0 bank conflicts
#define NBLK    ((N_NODES + 255) / 256)   // 391

#define NBUCK   196       // dst buckets of 512 nodes: 196*512 = 100352 >= N_NODES
#define BSH     9         // bucket shift (512 nodes)
#define EPB     4096      // edges per partition block
#define NPART   ((N_EDGES + EPB - 1) / EPB)   // 782
#define C2SPLIT 4

// index load robust to int32/int64 (is32 nonzero => int32)
__device__ __forceinline__ int load_idx(const void* ei, int is32, long long pos) {
    return is32 ? ((const int*)ei)[pos] : (int)((const long long*)ei)[pos];
}

__global__ void k_zeroi(int* __restrict__ p, int n) {
    int i = blockIdx.x * 256 + threadIdx.x;
    if (i < n) p[i] = 0;
}

// int64 storage (values < 2^31) => all odd 32-bit words are 0; int32 => mostly nonzero.
__global__ void k_detect(const unsigned* __restrict__ ei, int* __restrict__ det) {
    int t = threadIdx.x;
    unsigned odd = 0;
    for (int i = t; i < 4096; i += 256) odd |= ei[2 * i + 1];   // 32KB read, safe either way
    if (odd) atomicOr(&det[0], 1);
}

// per-block LDS histogram of dst buckets -> global bucket sizes
__global__ __launch_bounds__(256) void k_bhist(const void* __restrict__ ei,
                                               const int* __restrict__ det,
                                               int* __restrict__ bsize) {
    __shared__ int hist[NBUCK];
    int t = threadIdx.x;
    long long e0 = (long long)blockIdx.x * EPB;
    long long e1 = e0 + EPB; if (e1 > N_EDGES) e1 = N_EDGES;
    int is32 = det[0];
    if (t < NBUCK) hist[t] = 0;
    __syncthreads();
    for (long long e = e0 + t; e < e1; e += 256) {
        int d = load_idx(ei, is32, N_EDGES + e);
        atomicAdd(&hist[d >> BSH], 1);
    }
    __syncthreads();
    if (t < NBUCK && hist[t]) atomicAdd(&bsize[t], hist[t]);
}

// exclusive scan of 196 bucket sizes -> bbase (read-only) and bcur (atomic cursors)
__global__ void k_bucketscan(const int* __restrict__ bsize, int* __restrict__ bbase,
                             int* __restrict__ bcur) {
    __shared__ int s[256];
    int t = threadIdx.x;
    int v = (t < NBUCK) ? bsize[t] : 0;
    s[t] = v;
    __syncthreads();
    for (int off = 1; off < 256; off <<= 1) {
        int u = (t >= off) ? s[t - off] : 0;
        __syncthreads();
        s[t] += u;
        __syncthreads();
    }
    if (t < NBUCK) { int ex = s[t] - v; bbase[t] = ex; bcur[t] = ex; }
}

// partition edges into dst buckets; packed word = (s<<9)|(d&511) (26 bits)
__global__ __launch_bounds__(256) void k_part(const void* __restrict__ ei,
                                              const int* __restrict__ det,
                                              int* __restrict__ bcur,
                                              unsigned* __restrict__ buf) {
    __shared__ int hist[NBUCK];
    __shared__ int base[NBUCK];
    __shared__ int lcur[NBUCK];
    int t = threadIdx.x;
    long long e0 = (long long)blockIdx.x * EPB;
    long long e1 = e0 + EPB; if (e1 > N_EDGES) e1 = N_EDGES;
    int is32 = det[0];
    if (t < NBUCK) { hist[t] = 0; lcur[t] = 0; }
    __syncthreads();
    for (long long e = e0 + t; e < e1; e += 256) {
        int d = load_idx(ei, is32, N_EDGES + e);
        atomicAdd(&hist[d >> BSH], 1);
    }
    __syncthreads();
    if (t < NBUCK) base[t] = hist[t] ? atomicAdd(&bcur[t], hist[t]) : 0;
    __syncthreads();
    for (long long e = e0 + t; e < e1; e += 256) {
        int s = load_idx(ei, is32, e);
        int d = load_idx(ei, is32, (long long)N_EDGES + e);
        int b = d >> BSH;
        int off = atomicAdd(&lcur[b], 1);
        buf[base[b] + off] = ((unsigned)s << BSH) | (unsigned)(d & 511);
    }
}

// recover per-node in-degree from the partition via LDS counters (no global atomics);
// also emits dinv = rsqrt(deg+1) directly.
__global__ __launch_bounds__(256) void k_degb(const unsigned* __restrict__ buf,
                                              const int* __restrict__ bbase,
                                              const int* __restrict__ bsize,
                                              int* __restrict__ deg,
                                              float* __restrict__ dinv) {
    __shared__ int cnt[512];
    int t = threadIdx.x;
    int b = blockIdx.x;
    cnt[t] = 0; cnt[t + 256] = 0;
    __syncthreads();
    int j0 = bbase[b], j1 = j0 + bsize[b];
    for (int j = j0 + t; j < j1; j += 256)
        atomicAdd(&cnt[buf[j] & 511], 1);
    __syncthreads();
    int n = (b << BSH) + t;
    if (n < N_NODES) { deg[n] = cnt[t]; dinv[n] = rsqrtf((float)(cnt[t] + 1)); }
    n += 256;
    if (n < N_NODES) { deg[n] = cnt[t + 256]; dinv[n] = rsqrtf((float)(cnt[t + 256] + 1)); }
}

// ---- two-level exclusive scan of deg -> rowptr ----
__global__ void k_bsum(const int* __restrict__ deg, int* __restrict__ bsum) {
    __shared__ int s[256];
    int t = threadIdx.x;
    int i = blockIdx.x * 256 + t;
    s[t] = (i < N_NODES) ? deg[i] : 0;
    __syncthreads();
    for (int off = 128; off > 0; off >>= 1) {
        if (t < off) s[t] += s[t + off];
        __syncthreads();
    }
    if (t == 0) bsum[blockIdx.x] = s[0];
}

__global__ void k_bscan(const int* __restrict__ bsum, int* __restrict__ boff, int nb) {
    __shared__ int s[512];
    int t = threadIdx.x;
    s[t] = (t < nb) ? bsum[t] : 0;
    __syncthreads();
    for (int off = 1; off < 512; off <<= 1) {
        int u = (t >= off) ? s[t - off] : 0;
        __syncthreads();
        s[t] += u;
        __syncthreads();
    }
    if (t < nb) boff[t] = (t == 0) ? 0 : s[t - 1];
}

// per-block exclusive scan + block offset; ALSO turns deg[] into cursor[] (copy of rowptr)
__global__ void k_rowptr(int* __restrict__ deg, const int* __restrict__ boff,
                         int* __restrict__ rowptr) {
    __shared__ int s[256];
    int t = threadIdx.x;
    int i = blockIdx.x * 256 + t;
    int v = (i < N_NODES) ? deg[i] : 0;
    s[t] = v;
    __syncthreads();
    for (int off = 1; off < 256; off <<= 1) {
        int u = (t >= off) ? s[t - off] : 0;
        __syncthreads();
        s[t] += u;
        __syncthreads();
    }
    if (i < N_NODES) {
        int ex = s[t] - v + boff[blockIdx.x];
        rowptr[i] = ex;
        deg[i] = ex;                 // cursor for k_place2
        if (i == N_NODES - 1) rowptr[N_NODES] = ex + v;  // == N_EDGES
    }
}

// place bucket-partitioned edges into CSR; csr writes stay in a ~64KB L2 window
__global__ __launch_bounds__(256) void k_place2(const unsigned* __restrict__ buf,
                                                const int* __restrict__ bbase,
                                                const int* __restrict__ bsize,
                                                int* __restrict__ cursor,
                                                int* __restrict__ csr) {
    int b = blockIdx.x / C2SPLIT;
    int c = blockIdx.x % C2SPLIT;
    int sz = bsize[b], base = bbase[b];
    int j0 = base + (int)((long long)sz * c / C2SPLIT);
    int j1 = base + (int)((long long)sz * (c + 1) / C2SPLIT);
    for (int j = j0 + threadIdx.x; j < j1; j += 256) {
        unsigned p = buf[j];
        int d = (b << BSH) | (int)(p & 511);
        int s = (int)(p >> BSH);
        int pos = atomicAdd(&cursor[d], 1);
        csr[pos] = s;
    }
}

// W1 [512][16] -> Wt [16][512]
__global__ void k_wt(const float* __restrict__ W1, float* __restrict__ Wt) {
    int t = blockIdx.x * 256 + threadIdx.x;
    if (t < F_IN * HIDDEN) {
        int k = t >> 9;
        int j = t & (F_IN - 1);
        Wt[t] = W1[j * HIDDEN + k];
    }
}

// hs[N][16] = (x @ W1) * dinv[row].
// 64-row tile (17.4KB LDS), 1563 blocks (~6/CU), register-prefetch pipeline:
// chunk ch+1's global loads issue before chunk ch's compute -> HBM latency hides.
__global__ __launch_bounds__(256) void k_gemm1(const float* __restrict__ x,
                                               const float* __restrict__ Wt,
                                               const float* __restrict__ dinv,
                                               float* __restrict__ hs) {
    __shared__ float sX[TILE_R * XSTRIDE];
    int t = threadIdx.x;
    int lane = t & 63;
    int rowbase = blockIdx.x * TILE_R;
    int kbase = __builtin_amdgcn_readfirstlane((t >> 6) << 2);   // 0,4,8,12
    const float* wk = Wt + kbase * F_IN;

    // staging map: f = i*256+t in 0..1023; row=f>>4 (0..63), c4=f&15
    float4 r[4];
#pragma unroll
    for (int i = 0; i < 4; ++i) {
        int f = i * 256 + t, row = f >> 4, c4 = f & 15;
        int grow = rowbase + row;
        r[i] = make_float4(0.f, 0.f, 0.f, 0.f);
        if (grow < N_NODES)
            r[i] = ((const float4*)(x + (size_t)grow * F_IN))[c4];
    }
    float acc[4] = {};
#pragma unroll 1
    for (int ch = 0; ch < F_IN / KC; ++ch) {
        // store staged regs to LDS
#pragma unroll
        for (int i = 0; i < 4; ++i) {
            int f = i * 256 + t, row = f >> 4, c4 = f & 15;
            *((float4*)&sX[row * XSTRIDE + c4 * 4]) = r[i];
        }
        __syncthreads();
        // prefetch next chunk into regs (overlaps with compute below)
        if (ch + 1 < F_IN / KC) {
#pragma unroll
            for (int i = 0; i < 4; ++i) {
                int f = i * 256 + t, row = f >> 4, c4 = f & 15;
                int grow = rowbase + row;
                r[i] = make_float4(0.f, 0.f, 0.f, 0.f);
                if (grow < N_NODES)
                    r[i] = ((const float4*)(x + (size_t)grow * F_IN + (ch + 1) * KC))[c4];
            }
        }
        // compute: lane owns row `lane`; wave owns cols kbase..kbase+3 (W wave-uniform -> s_load)
#pragma unroll
        for (int js = 0; js < KC; js += 4) {
            float4 xv = *((const float4*)&sX[lane * XSTRIDE + js]);
#pragma unroll
            for (int kk = 0; kk < 4; ++kk) {
                const float* wp = wk + kk * F_IN + ch * KC + js;
                acc[kk] += xv.x * wp[0] + xv.y * wp[1] + xv.z * wp[2] + xv.w * wp[3];
            }
        }
        __syncthreads();   // all reads done before next iteration's store
    }
    int grow = rowbase + lane;
    if (grow < N_NODES) {
        float di = dinv[grow];
        *((float4*)&hs[(size_t)grow * HIDDEN + kbase]) =
            make_float4(acc[0] * di, acc[1] * di, acc[2] * di, acc[3] * di);
    }
}

// layer-1 gather-aggregate (atomic-free) + bias + ReLU + (16->10)W2 + dinv pre-scale
__global__ __launch_bounds__(256) void k_agg1(const int* __restrict__ rowptr,
                                              const int* __restrict__ csr,
                                              const float* __restrict__ hs,
                                              const float* __restrict__ dinv,
                                              const float* __restrict__ b1,
                                              const float* __restrict__ W2,
                                              float* __restrict__ ts) {
    __shared__ float sh[16][17];
    int t  = threadIdx.x;
    int ln = t >> 4;          // local node 0..15
    int k  = t & 15;          // feature lane
    int n  = blockIdx.x * 16 + ln;
    bool valid = n < N_NODES;
    int r0 = valid ? rowptr[n] : 0;
    int r1 = valid ? rowptr[n + 1] : 0;
    float acc = valid ? hs[(size_t)n * HIDDEN + k] : 0.f;   // self-loop (already *dinv[n])
    int j = r0;
    for (; j + 4 <= r1; j += 4) {
        int s0 = csr[j], s1 = csr[j + 1], s2 = csr[j + 2], s3 = csr[j + 3];
        float v0 = hs[(size_t)s0 * HIDDEN + k];
        float v1 = hs[(size_t)s1 * HIDDEN + k];
        float v2 = hs[(size_t)s2 * HIDDEN + k];
        float v3 = hs[(size_t)s3 * HIDDEN + k];
        acc += (v0 + v1) + (v2 + v3);
    }
    for (; j < r1; ++j) acc += hs[(size_t)csr[j] * HIDDEN + k];
    float di = valid ? dinv[n] : 0.f;
    float h = di * acc + b1[k];
    sh[ln][k] = h > 0.f ? h : 0.f;
    __syncthreads();
    int c = (k < N_CLASS) ? k : 0;
    float o = 0.f;
#pragma unroll
    for (int kk = 0; kk < HIDDEN; ++kk) o += sh[ln][kk] * W2[kk * N_CLASS + c];
    if (valid) ts[(size_t)n * 16 + k] = (k < N_CLASS) ? o * di : 0.f;
}

// layer-2 gather-aggregate (atomic-free) + bias -> out
__global__ __launch_bounds__(256) void k_agg2(const int* __restrict__ rowptr,
                                              const int* __restrict__ csr,
                                              const float* __restrict__ ts,
                                              const float* __restrict__ dinv,
                                              const float* __restrict__ b2,
                                              float* __restrict__ out) {
    int t  = threadIdx.x;
    int ln = t >> 4;
    int c  = t & 15;
    int n  = blockIdx.x * 16 + ln;
    if (n >= N_NODES) return;
    int r0 = rowptr[n], r1 = rowptr[n + 1];
    float acc = ts[(size_t)n * 16 + c];    // self-loop (already *dinv[n])
    int j = r0;
    for (; j + 4 <= r1; j += 4) {
        int s0 = csr[j], s1 = csr[j + 1], s2 = csr[j + 2], s3 = csr[j + 3];
        float v0 = ts[(size_t)s0 * 16 + c];
        float v1 = ts[(size_t)s1 * 16 + c];
        float v2 = ts[(size_t)s2 * 16 + c];
        float v3 = ts[(size_t)s3 * 16 + c];
        acc += (v0 + v1) + (v2 + v3);
    }
    for (; j < r1; ++j) acc += ts[(size_t)csr[j] * 16 + c];
    if (c < N_CLASS) out[(size_t)n * N_CLASS + c] = dinv[n] * acc + b2[c];
}

extern "C" void kernel_launch(void* const* d_in, const int* in_sizes, int n_in,
                              void* d_out, int out_size, void* d_ws, size_t ws_size,
                              hipStream_t stream) {
    const float* x  = (const float*)d_in[0];   // fp32 [N,512]
    const void*  ei = d_in[1];                 // int64 (int32 handled via probe)
    const float* W1 = (const float*)d_in[2];   // fp32 [512,16]
    const float* b1 = (const float*)d_in[3];   // fp32 [16]
    const float* W2 = (const float*)d_in[4];   // fp32 [16,10]
    const float* b2 = (const float*)d_in[5];   // fp32 [10]
    float* out = (float*)d_out;                // fp32 [N,10]
    float* ws  = (float*)d_ws;

    // ws layout (4-byte units), ~26.9 MB total
    float* dinv   = ws;                        // 100,096
    int*   deg    = (int*)(ws + 100096);       // 100,096  (becomes cursor)
    int*   rowptr = (int*)(ws + 200192);       // 100,416  (N+1, padded)
    int*   bsum   = (int*)(ws + 300608);       // 512
    int*   boff   = (int*)(ws + 301120);       // 512
    int*   bsize  = (int*)(ws + 301632);       // 256
    int*   bbase  = (int*)(ws + 301888);       // 256
    int*   bcur   = (int*)(ws + 302144);       // 256
    int*   det    = (int*)(ws + 302400);       // 64
    int*   csr    = (int*)(ws + 302464);       // 3,200,000
    float* hs     = ws + 3502464;              // 1,600,000
    float* ts     = ws + 5102464;              // 1,600,000
    float* Wt     = ws + 6702464;              // 8,192
    // buf (3.2M uint32) overlays hs+ts: dead before k_gemm1 writes hs
    unsigned* buf = (unsigned*)(ws + 3502464);

    k_zeroi <<<1, 256, 0, stream>>>(bsize, NBUCK);
    k_zeroi <<<1, 64, 0, stream>>>(det, 1);
    k_detect<<<1, 256, 0, stream>>>((const unsigned*)ei, det);

    k_bhist     <<<NPART, 256, 0, stream>>>(ei, det, bsize);
    k_bucketscan<<<1, 256, 0, stream>>>(bsize, bbase, bcur);
    k_part      <<<NPART, 256, 0, stream>>>(ei, det, bcur, buf);
    k_degb      <<<NBUCK, 256, 0, stream>>>(buf, bbase, bsize, deg, dinv);

    k_bsum  <<<NBLK, 256, 0, stream>>>(deg, bsum);
    k_bscan <<<1, 512, 0, stream>>>(bsum, boff, NBLK);
    k_rowptr<<<NBLK, 256, 0, stream>>>(deg, boff, rowptr);
    k_place2<<<NBUCK * C2SPLIT, 256, 0, stream>>>(buf, bbase, bsize, deg /*cursor*/, csr);

    k_wt    <<<(F_IN * HIDDEN) / 256, 256, 0, stream>>>(W1, Wt);
    k_gemm1 <<<(N_NODES + TILE_R - 1) / TILE_R, 256, 0, stream>>>(x, Wt, dinv, hs);

    k_agg1  <<<(N_NODES + 15) / 16, 256, 0, stream>>>(rowptr, csr, hs, dinv, b1, W2, ts);
    k_agg2  <<<(N_NODES + 15) / 16, 256, 0, stream>>>(rowptr, csr, ts, dinv, b2, out);
}

// Round 7
// 548.766 us; speedup vs baseline: 2.0295x; 1.1425x over previous
//
#include <hip/hip_runtime.h>

#define N_NODES 100000
#define N_EDGES 3200000
#define F_IN    512
#define HIDDEN  16
#define N_CLASS 10

#define TILE_R  64
#define KC      64
#define XSTRIDE 68   // padded LDS stride (floats); %4==0 for b128, measured 0 bank conflicts
#define NBLK    ((N_NODES + 255) / 256)   // 391

#define NBUCK   196       // dst buckets of 512 nodes: 196*512 = 100352 >= N_NODES
#define BSH     9         // bucket shift (512 nodes)
#define EPB     4096      // edges per partition block
#define NPART   ((N_EDGES + EPB - 1) / EPB)   // 782
#define PCAP    18432     // LDS staging cap per bucket (mean 16326 + 16 sigma; guarded fallback)

// index load robust to int32/int64 (is32 nonzero => int32)
__device__ __forceinline__ int load_idx(const void* ei, int is32, long long pos) {
    return is32 ? ((const int*)ei)[pos] : (int)((const long long*)ei)[pos];
}

__global__ void k_zeroi(int* __restrict__ p, int n) {
    int i = blockIdx.x * 256 + threadIdx.x;
    if (i < n) p[i] = 0;
}

// int64 storage (values < 2^31) => all odd 32-bit words are 0; int32 => mostly nonzero.
__global__ void k_detect(const unsigned* __restrict__ ei, int* __restrict__ det) {
    int t = threadIdx.x;
    unsigned odd = 0;
    for (int i = t; i < 4096; i += 256) odd |= ei[2 * i + 1];   // 32KB read, safe either way
    if (odd) atomicOr(&det[0], 1);
}

// per-block LDS histogram of dst buckets -> global bucket sizes
__global__ __launch_bounds__(256) void k_bhist(const void* __restrict__ ei,
                                               const int* __restrict__ det,
                                               int* __restrict__ bsize) {
    __shared__ int hist[NBUCK];
    int t = threadIdx.x;
    long long e0 = (long long)blockIdx.x * EPB;
    long long e1 = e0 + EPB; if (e1 > N_EDGES) e1 = N_EDGES;
    int is32 = det[0];
    if (t < NBUCK) hist[t] = 0;
    __syncthreads();
    for (long long e = e0 + t; e < e1; e += 256) {
        int d = load_idx(ei, is32, N_EDGES + e);
        atomicAdd(&hist[d >> BSH], 1);
    }
    __syncthreads();
    if (t < NBUCK && hist[t]) atomicAdd(&bsize[t], hist[t]);
}

// exclusive scan of 196 bucket sizes -> bbase (read-only) and bcur (atomic cursors)
__global__ void k_bucketscan(const int* __restrict__ bsize, int* __restrict__ bbase,
                             int* __restrict__ bcur) {
    __shared__ int s[256];
    int t = threadIdx.x;
    int v = (t < NBUCK) ? bsize[t] : 0;
    s[t] = v;
    __syncthreads();
    for (int off = 1; off < 256; off <<= 1) {
        int u = (t >= off) ? s[t - off] : 0;
        __syncthreads();
        s[t] += u;
        __syncthreads();
    }
    if (t < NBUCK) { int ex = s[t] - v; bbase[t] = ex; bcur[t] = ex; }
}

// partition edges into dst buckets; packed word = (s<<9)|(d&511) (26 bits)
__global__ __launch_bounds__(256) void k_part(const void* __restrict__ ei,
                                              const int* __restrict__ det,
                                              int* __restrict__ bcur,
                                              unsigned* __restrict__ buf) {
    __shared__ int hist[NBUCK];
    __shared__ int base[NBUCK];
    __shared__ int lcur[NBUCK];
    int t = threadIdx.x;
    long long e0 = (long long)blockIdx.x * EPB;
    long long e1 = e0 + EPB; if (e1 > N_EDGES) e1 = N_EDGES;
    int is32 = det[0];
    if (t < NBUCK) { hist[t] = 0; lcur[t] = 0; }
    __syncthreads();
    for (long long e = e0 + t; e < e1; e += 256) {
        int d = load_idx(ei, is32, N_EDGES + e);
        atomicAdd(&hist[d >> BSH], 1);
    }
    __syncthreads();
    if (t < NBUCK) base[t] = hist[t] ? atomicAdd(&bcur[t], hist[t]) : 0;
    __syncthreads();
    for (long long e = e0 + t; e < e1; e += 256) {
        int s = load_idx(ei, is32, e);
        int d = load_idx(ei, is32, (long long)N_EDGES + e);
        int b = d >> BSH;
        int off = atomicAdd(&lcur[b], 1);
        buf[base[b] + off] = ((unsigned)s << BSH) | (unsigned)(d & 511);
    }
}

// recover per-node in-degree from the partition via LDS counters (no global atomics);
// also emits dinv = rsqrt(deg+1) directly.
__global__ __launch_bounds__(256) void k_degb(const unsigned* __restrict__ buf,
                                              const int* __restrict__ bbase,
                                              const int* __restrict__ bsize,
                                              int* __restrict__ deg,
                                              float* __restrict__ dinv) {
    __shared__ int cnt[512];
    int t = threadIdx.x;
    int b = blockIdx.x;
    cnt[t] = 0; cnt[t + 256] = 0;
    __syncthreads();
    int j0 = bbase[b], j1 = j0 + bsize[b];
    for (int j = j0 + t; j < j1; j += 256)
        atomicAdd(&cnt[buf[j] & 511], 1);
    __syncthreads();
    int n = (b << BSH) + t;
    if (n < N_NODES) { deg[n] = cnt[t]; dinv[n] = rsqrtf((float)(cnt[t] + 1)); }
    n += 256;
    if (n < N_NODES) { deg[n] = cnt[t + 256]; dinv[n] = rsqrtf((float)(cnt[t + 256] + 1)); }
}

// ---- two-level exclusive scan of deg -> rowptr ----
__global__ void k_bsum(const int* __restrict__ deg, int* __restrict__ bsum) {
    __shared__ int s[256];
    int t = threadIdx.x;
    int i = blockIdx.x * 256 + t;
    s[t] = (i < N_NODES) ? deg[i] : 0;
    __syncthreads();
    for (int off = 128; off > 0; off >>= 1) {
        if (t < off) s[t] += s[t + off];
        __syncthreads();
    }
    if (t == 0) bsum[blockIdx.x] = s[0];
}

__global__ void k_bscan(const int* __restrict__ bsum, int* __restrict__ boff, int nb) {
    __shared__ int s[512];
    int t = threadIdx.x;
    s[t] = (t < nb) ? bsum[t] : 0;
    __syncthreads();
    for (int off = 1; off < 512; off <<= 1) {
        int u = (t >= off) ? s[t - off] : 0;
        __syncthreads();
        s[t] += u;
        __syncthreads();
    }
    if (t < nb) boff[t] = (t == 0) ? 0 : s[t - 1];
}

// per-block exclusive scan + block offset -> rowptr
__global__ void k_rowptr(const int* __restrict__ deg, const int* __restrict__ boff,
                         int* __restrict__ rowptr) {
    __shared__ int s[256];
    int t = threadIdx.x;
    int i = blockIdx.x * 256 + t;
    int v = (i < N_NODES) ? deg[i] : 0;
    s[t] = v;
    __syncthreads();
    for (int off = 1; off < 256; off <<= 1) {
        int u = (t >= off) ? s[t - off] : 0;
        __syncthreads();
        s[t] += u;
        __syncthreads();
    }
    if (i < N_NODES) {
        int ex = s[t] - v + boff[blockIdx.x];
        rowptr[i] = ex;
        if (i == N_NODES - 1) rowptr[N_NODES] = ex + v;  // == N_EDGES
    }
}

// CSR placement with LDS staging: one block per bucket.
// Positions resolved via LDS cursors (rowptr[n]-csrbase), src scattered into an LDS
// buffer, then streamed to csr with fully-coalesced stores (kills the 12.7x write amp).
// Invariant: bbase[b] == rowptr[b<<BSH] (both prefix-sum the same per-bucket counts).
__global__ __launch_bounds__(256) void k_place3(const unsigned* __restrict__ buf,
                                                const int* __restrict__ bbase,
                                                const int* __restrict__ bsize,
                                                const int* __restrict__ rowptr,
                                                int* __restrict__ csr) {
    __shared__ int lptr[512];
    __shared__ int outb[PCAP];
    int t = threadIdx.x;
    int b = blockIdx.x;
    int jb = bbase[b];           // buf segment base
    int sz = bsize[b];
    int nb0 = b << BSH;
    int csrbase = rowptr[nb0];   // == jb
    for (int i = t; i < 512; i += 256) {
        int n = nb0 + i;
        lptr[i] = (n < N_NODES) ? rowptr[n] - csrbase : sz;
    }
    __syncthreads();
    for (int j = t; j < sz; j += 256) {
        unsigned p = buf[jb + j];
        int pos = atomicAdd(&lptr[p & 511], 1);
        int s = (int)(p >> BSH);
        if (pos < PCAP) outb[pos] = s;
        else            csr[csrbase + pos] = s;   // statistically unreachable fallback
    }
    __syncthreads();
    int lim = sz < PCAP ? sz : PCAP;
    for (int j = t; j < lim; j += 256) csr[csrbase + j] = outb[j];
}

// W1 [512][16] -> Wt [16][512]
__global__ void k_wt(const float* __restrict__ W1, float* __restrict__ Wt) {
    int t = blockIdx.x * 256 + threadIdx.x;
    if (t < F_IN * HIDDEN) {
        int k = t >> 9;
        int j = t & (F_IN - 1);
        Wt[t] = W1[j * HIDDEN + k];
    }
}

// hs[N][16] = (x @ W1) * dinv[row].
// 64-row tile (17.4KB LDS), 1563 blocks (~6/CU), register-prefetch pipeline:
// chunk ch+1's global loads issue before chunk ch's compute -> HBM latency hides.
__global__ __launch_bounds__(256) void k_gemm1(const float* __restrict__ x,
                                               const float* __restrict__ Wt,
                                               const float* __restrict__ dinv,
                                               float* __restrict__ hs) {
    __shared__ float sX[TILE_R * XSTRIDE];
    int t = threadIdx.x;
    int lane = t & 63;
    int rowbase = blockIdx.x * TILE_R;
    int kbase = __builtin_amdgcn_readfirstlane((t >> 6) << 2);   // 0,4,8,12
    const float* wk = Wt + kbase * F_IN;

    // staging map: f = i*256+t in 0..1023; row=f>>4 (0..63), c4=f&15
    float4 r[4];
#pragma unroll
    for (int i = 0; i < 4; ++i) {
        int f = i * 256 + t, row = f >> 4, c4 = f & 15;
        int grow = rowbase + row;
        r[i] = make_float4(0.f, 0.f, 0.f, 0.f);
        if (grow < N_NODES)
            r[i] = ((const float4*)(x + (size_t)grow * F_IN))[c4];
    }
    float acc[4] = {};
#pragma unroll 1
    for (int ch = 0; ch < F_IN / KC; ++ch) {
        // store staged regs to LDS
#pragma unroll
        for (int i = 0; i < 4; ++i) {
            int f = i * 256 + t, row = f >> 4, c4 = f & 15;
            *((float4*)&sX[row * XSTRIDE + c4 * 4]) = r[i];
        }
        __syncthreads();
        // prefetch next chunk into regs (overlaps with compute below)
        if (ch + 1 < F_IN / KC) {
#pragma unroll
            for (int i = 0; i < 4; ++i) {
                int f = i * 256 + t, row = f >> 4, c4 = f & 15;
                int grow = rowbase + row;
                r[i] = make_float4(0.f, 0.f, 0.f, 0.f);
                if (grow < N_NODES)
                    r[i] = ((const float4*)(x + (size_t)grow * F_IN + (ch + 1) * KC))[c4];
            }
        }
        // compute: lane owns row `lane`; wave owns cols kbase..kbase+3 (W wave-uniform -> s_load)
#pragma unroll
        for (int js = 0; js < KC; js += 4) {
            float4 xv = *((const float4*)&sX[lane * XSTRIDE + js]);
#pragma unroll
            for (int kk = 0; kk < 4; ++kk) {
                const float* wp = wk + kk * F_IN + ch * KC + js;
                acc[kk] += xv.x * wp[0] + xv.y * wp[1] + xv.z * wp[2] + xv.w * wp[3];
            }
        }
        __syncthreads();   // all reads done before next iteration's store
    }
    int grow = rowbase + lane;
    if (grow < N_NODES) {
        float di = dinv[grow];
        *((float4*)&hs[(size_t)grow * HIDDEN + kbase]) =
            make_float4(acc[0] * di, acc[1] * di, acc[2] * di, acc[3] * di);
    }
}

// layer-1 gather-aggregate (atomic-free) + bias + ReLU + (16->10)W2 + dinv pre-scale
__global__ __launch_bounds__(256) void k_agg1(const int* __restrict__ rowptr,
                                              const int* __restrict__ csr,
                                              const float* __restrict__ hs,
                                              const float* __restrict__ dinv,
                                              const float* __restrict__ b1,
                                              const float* __restrict__ W2,
                                              float* __restrict__ ts) {
    __shared__ float sh[16][17];
    int t  = threadIdx.x;
    int ln = t >> 4;          // local node 0..15
    int k  = t & 15;          // feature lane
    int n  = blockIdx.x * 16 + ln;
    bool valid = n < N_NODES;
    int r0 = valid ? rowptr[n] : 0;
    int r1 = valid ? rowptr[n + 1] : 0;
    float acc = valid ? hs[(size_t)n * HIDDEN + k] : 0.f;   // self-loop (already *dinv[n])
    int j = r0;
    for (; j + 4 <= r1; j += 4) {
        int s0 = csr[j], s1 = csr[j + 1], s2 = csr[j + 2], s3 = csr[j + 3];
        float v0 = hs[(size_t)s0 * HIDDEN + k];
        float v1 = hs[(size_t)s1 * HIDDEN + k];
        float v2 = hs[(size_t)s2 * HIDDEN + k];
        float v3 = hs[(size_t)s3 * HIDDEN + k];
        acc += (v0 + v1) + (v2 + v3);
    }
    for (; j < r1; ++j) acc += hs[(size_t)csr[j] * HIDDEN + k];
    float di = valid ? dinv[n] : 0.f;
    float h = di * acc + b1[k];
    sh[ln][k] = h > 0.f ? h : 0.f;
    __syncthreads();
    int c = (k < N_CLASS) ? k : 0;
    float o = 0.f;
#pragma unroll
    for (int kk = 0; kk < HIDDEN; ++kk) o += sh[ln][kk] * W2[kk * N_CLASS + c];
    if (valid) ts[(size_t)n * 16 + k] = (k < N_CLASS) ? o * di : 0.f;
}

// layer-2 gather-aggregate (atomic-free) + bias -> out
__global__ __launch_bounds__(256) void k_agg2(const int* __restrict__ rowptr,
                                              const int* __restrict__ csr,
                                              const float* __restrict__ ts,
                                              const float* __restrict__ dinv,
                                              const float* __restrict__ b2,
                                              float* __restrict__ out) {
    int t  = threadIdx.x;
    int ln = t >> 4;
    int c  = t & 15;
    int n  = blockIdx.x * 16 + ln;
    if (n >= N_NODES) return;
    int r0 = rowptr[n], r1 = rowptr[n + 1];
    float acc = ts[(size_t)n * 16 + c];    // self-loop (already *dinv[n])
    int j = r0;
    for (; j + 4 <= r1; j += 4) {
        int s0 = csr[j], s1 = csr[j + 1], s2 = csr[j + 2], s3 = csr[j + 3];
        float v0 = ts[(size_t)s0 * 16 + c];
        float v1 = ts[(size_t)s1 * 16 + c];
        float v2 = ts[(size_t)s2 * 16 + c];
        float v3 = ts[(size_t)s3 * 16 + c];
        acc += (v0 + v1) + (v2 + v3);
    }
    for (; j < r1; ++j) acc += ts[(size_t)csr[j] * 16 + c];
    if (c < N_CLASS) out[(size_t)n * N_CLASS + c] = dinv[n] * acc + b2[c];
}

extern "C" void kernel_launch(void* const* d_in, const int* in_sizes, int n_in,
                              void* d_out, int out_size, void* d_ws, size_t ws_size,
                              hipStream_t stream) {
    const float* x  = (const float*)d_in[0];   // fp32 [N,512]
    const void*  ei = d_in[1];                 // int64 (int32 handled via probe)
    const float* W1 = (const float*)d_in[2];   // fp32 [512,16]
    const float* b1 = (const float*)d_in[3];   // fp32 [16]
    const float* W2 = (const float*)d_in[4];   // fp32 [16,10]
    const float* b2 = (const float*)d_in[5];   // fp32 [10]
    float* out = (float*)d_out;                // fp32 [N,10]
    float* ws  = (float*)d_ws;

    // ws layout (4-byte units), ~26.9 MB total
    float* dinv   = ws;                        // 100,096
    int*   deg    = (int*)(ws + 100096);       // 100,096
    int*   rowptr = (int*)(ws + 200192);       // 100,416  (N+1, padded)
    int*   bsum   = (int*)(ws + 300608);       // 512
    int*   boff   = (int*)(ws + 301120);       // 512
    int*   bsize  = (int*)(ws + 301632);       // 256
    int*   bbase  = (int*)(ws + 301888);       // 256
    int*   bcur   = (int*)(ws + 302144);       // 256
    int*   det    = (int*)(ws + 302400);       // 64
    int*   csr    = (int*)(ws + 302464);       // 3,200,000
    float* hs     = ws + 3502464;              // 1,600,000
    float* ts     = ws + 5102464;              // 1,600,000
    float* Wt     = ws + 6702464;              // 8,192
    // buf (3.2M uint32) overlays hs+ts: dead before k_gemm1 writes hs
    unsigned* buf = (unsigned*)(ws + 3502464);

    k_zeroi <<<1, 256, 0, stream>>>(bsize, NBUCK);
    k_zeroi <<<1, 64, 0, stream>>>(det, 1);
    k_detect<<<1, 256, 0, stream>>>((const unsigned*)ei, det);

    k_bhist     <<<NPART, 256, 0, stream>>>(ei, det, bsize);
    k_bucketscan<<<1, 256, 0, stream>>>(bsize, bbase, bcur);
    k_part      <<<NPART, 256, 0, stream>>>(ei, det, bcur, buf);
    k_degb      <<<NBUCK, 256, 0, stream>>>(buf, bbase, bsize, deg, dinv);

    k_bsum  <<<NBLK, 256, 0, stream>>>(deg, bsum);
    k_bscan <<<1, 512, 0, stream>>>(bsum, boff, NBLK);
    k_rowptr<<<NBLK, 256, 0, stream>>>(deg, boff, rowptr);
    k_place3<<<NBUCK, 256, 0, stream>>>(buf, bbase, bsize, rowptr, csr);

    k_wt    <<<(F_IN * HIDDEN) / 256, 256, 0, stream>>>(W1, Wt);
    k_gemm1 <<<(N_NODES + TILE_R - 1) / TILE_R, 256, 0, stream>>>(x, Wt, dinv, hs);

    k_agg1  <<<(N_NODES + 15) / 16, 256, 0, stream>>>(rowptr, csr, hs, dinv, b1, W2, ts);
    k_agg2  <<<(N_NODES + 15) / 16, 256, 0, stream>>>(rowptr, csr, ts, dinv, b2, out);
}